// Round 1
// 45930.228 us; speedup vs baseline: 1.4368x; 1.4368x over previous
//
#include <hip/hip_runtime.h>
#include <math.h>
#include <stdint.h>

// RHN round 3: kill the coherence-point contention.
//  - A-operand (state mirror) loads: plain cached 16B loads + per-phase
//    agent-acquire fence (buffer_inv) instead of per-8B agent-scope atomic
//    loads. L2 dedups the 64x cross-WG read duplication per XCD.
//  - Barrier: 4 per-depth monotone counters on separate 128B lines, single
//    poller per WG (tid 0), __syncthreads release, no s_sleep.
//  - hg0 prefetched into registers before the poll; carry loads issued
//    right after the fence so latency hides under the GEMM.
//  - exp2-based fast tanh/sigmoid in the epilogue.

#define SEQ 512
#define NB 64
#define HID 1024
#define NH2 2048
#define NL 2
#define ND 4
#define SBUF (NB * HID)                    // 65536
#define WSLOT ((size_t)NH2 * (size_t)HID)  // 2097152 elems per slot
#define MROWS (SEQ * NB)                   // 32768

typedef _Float16 half8 __attribute__((ext_vector_type(8)));
typedef float float4v __attribute__((ext_vector_type(4)));

// ---- workspace layout (bytes) ----
#define OFF_HG0 ((size_t)10 * WSLOT * 2)                 // 41943040  (Wt 40MB)
#define OFF_SSEQ (OFF_HG0 + (size_t)MROWS * NH2 * 2)     // +134217728
#define OFF_MIR (OFF_SSEQ + (size_t)MROWS * HID * 2)     // +67108864
#define OFF_CAR (OFF_MIR + (size_t)4 * SBUF * 2)         // 4 mirrors fp16
#define OFF_CNT (OFF_CAR + (size_t)2 * SBUF * 4)         // 2 carries fp32
// counters: 2 layers x 4 depths x 32-int (128B) stride = 1KB

__device__ __forceinline__ half8 ld8(const _Float16* p) {
    return *reinterpret_cast<const half8*>(p);
}

__device__ __forceinline__ half8 cvt8(const float* p) {
    const float4v a = *reinterpret_cast<const float4v*>(p);
    const float4v b = *reinterpret_cast<const float4v*>(p + 4);
    half8 r;
    r[0] = (_Float16)a[0]; r[1] = (_Float16)a[1];
    r[2] = (_Float16)a[2]; r[3] = (_Float16)a[3];
    r[4] = (_Float16)b[0]; r[5] = (_Float16)b[1];
    r[6] = (_Float16)b[2]; r[7] = (_Float16)b[3];
    return r;
}

// ---- prep: transpose+convert weights to fp16 [n][k] ----
// slots per layer l: l*5+0 = w_in[l]^T ; l*5+1..4 = w_h[l][d]^T
__global__ __launch_bounds__(256) void wprep(const float* __restrict__ w_in,
                                             const float* __restrict__ w_h,
                                             _Float16* __restrict__ Wt) {
    const int bid = (int)blockIdx.x;
    const int tk = bid & 31;
    const int tn = (bid >> 5) & 63;
    const int slot = bid >> 11;  // 0..9
    const int l = slot / 5;
    const int j = slot - l * 5;
    const float* __restrict__ src = (j == 0)
        ? (w_in + (size_t)l * WSLOT)
        : (w_h + (size_t)(l * ND + (j - 1)) * WSLOT);
    __shared__ float tile[32][33];
    const int tx = (int)(threadIdx.x & 31u);
    const int ty = (int)(threadIdx.x >> 5);
    const int n = tn * 32 + tx;
#pragma unroll
    for (int r = 0; r < 4; ++r) {
        const int k = tk * 32 + ty + r * 8;
        tile[ty + r * 8][tx] = src[(size_t)k * NH2 + n];
    }
    __syncthreads();
    _Float16* __restrict__ dst = Wt + (size_t)slot * WSLOT;
#pragma unroll
    for (int r = 0; r < 4; ++r) {
        const int nn = tn * 32 + ty + r * 8;
        const int kk = tk * 32 + tx;
        dst[(size_t)nn * HID + kk] = (_Float16)tile[tx][ty + r * 8];
    }
}

// ---- prep: init mirrors (fp16) + carries (fp32) + counters ----
__global__ void sinit2(const float* __restrict__ state, _Float16* __restrict__ mir0,
                       float* __restrict__ car0, _Float16* __restrict__ mir1,
                       float* __restrict__ car1, int* __restrict__ cnts) {
    const int i = (int)(blockIdx.x * 256 + threadIdx.x);
    if (i < SBUF) {
        const float v0 = state[i];
        const float v1 = state[SBUF + i];
        mir0[i] = (_Float16)v0; car0[i] = v0;
        mir1[i] = (_Float16)v1; car1[i] = v1;
    }
    if (i < 256) cnts[i] = 0;
}

// ---- bulk input-projection GEMM: C[m][n] = A[m][:] @ Bslot[n][:], fp16 out ----
template <bool AF16>
__global__ __launch_bounds__(256) void gemm_proj(const void* __restrict__ Av,
                                                 const _Float16* __restrict__ Bslot,
                                                 _Float16* __restrict__ C) {
    const int bid = (int)blockIdx.x;
    const int nt = bid & 31;    // 32 n-tiles of 64
    const int mt = bid >> 5;    // 512 m-tiles of 64
    const int lane = (int)(threadIdx.x & 63u);
    const int wv = (int)(threadIdx.x >> 6);
    const int lr = lane & 15;
    const int kofs = (lane >> 4) * 8;
    const int m = mt * 64 + wv * 16 + lr;
    float4v acc[4];
#pragma unroll
    for (int i = 0; i < 4; ++i) acc[i] = (float4v){0.f, 0.f, 0.f, 0.f};
#pragma unroll 4
    for (int kb = 0; kb < 32; ++kb) {
        half8 a;
        if (AF16) a = ld8((const _Float16*)Av + (size_t)m * HID + kb * 32 + kofs);
        else      a = cvt8((const float*)Av + (size_t)m * HID + kb * 32 + kofs);
#pragma unroll
        for (int ct = 0; ct < 4; ++ct) {
            const int n = nt * 64 + ct * 16 + lr;
            half8 b = ld8(Bslot + (size_t)n * HID + kb * 32 + kofs);
            acc[ct] = __builtin_amdgcn_mfma_f32_16x16x32_f16(a, b, acc[ct], 0, 0, 0);
        }
    }
#pragma unroll
    for (int ct = 0; ct < 4; ++ct) {
#pragma unroll
        for (int i = 0; i < 4; ++i) {
            const int row = mt * 64 + wv * 16 + (lane >> 4) * 4 + i;
            const int col = nt * 64 + ct * 16 + lr;
            const unsigned short mine =
                __builtin_bit_cast(unsigned short, (_Float16)acc[ct][i]);
            const unsigned short oth = (unsigned short)__shfl_xor((int)mine, 1, 64);
            if ((lane & 1) == 0) {
                const uint32_t pk = (uint32_t)mine | ((uint32_t)oth << 16);
                *reinterpret_cast<uint32_t*>(C + (size_t)row * NH2 + col) = pk;
            }
        }
    }
}

// ---- sequential scan over one layer: 512 t x 4 d phases ----
// 256 WGs: d = wg>>6 (depth specialization), cg = wg&63 (16 h-cols + 16 g-cols).
// Weights fragment-packed in 64KB dynamic LDS. 64 active WGs per phase.
// Sync: per-depth monotone counters (128B apart). Depth d time t waits for
// cnt[d-1] >= 64*(t+1) (d>0) / cnt[3] >= 64*t (d==0). One poller per WG,
// then __syncthreads + agent-acquire fence (invalidates stale L1/L2 so the
// state mirror can be read with plain cached loads).
__global__ __launch_bounds__(256) void rhn_scan(
    const _Float16* __restrict__ Wt, int slotBase,
    const float* __restrict__ bias,     // b_h[l] : [ND][NH2]
    const _Float16* __restrict__ hg0,   // [MROWS][NH2] fp16 precomputed proj
    _Float16* __restrict__ mirA, _Float16* __restrict__ mirB,  // state fp16 dbuf
    float* __restrict__ carry,          // [NB][HID] fp32 coherent carry
    int* __restrict__ cnt,              // [4][32] per-depth counters
    _Float16* __restrict__ sseq,        // layer0: [MROWS][HID] fp16 (else null)
    float* __restrict__ outp,           // layer1: [SEQ][NB][HID] fp32 (else null)
    float* __restrict__ fout) {         // final state [NB][HID] fp32
    extern __shared__ _Float16 lds[];   // [2 tiles][32 kb][64 lanes][8] = 64 KB
    const int wg = (int)blockIdx.x;
    const int d = wg >> 6;
    const int cg = wg & 63;
    const int tid = (int)threadIdx.x;
    const int lane = tid & 63;
    const int m0 = (tid >> 6) * 16;
    const int lr = lane & 15;
    const int kofs = (lane >> 4) * 8;
    const _Float16* __restrict__ slot = Wt + (size_t)(slotBase + d) * WSLOT;

    // fill LDS with packed B-fragments (once per scan)
    for (int i = 0; i < 16; ++i) {
        const int flat = i * 256 + tid;        // [tile][kb][lane]
        const int tile = flat >> 11;
        const int kb = (flat >> 6) & 31;
        const int ln = flat & 63;
        const int col = tile * HID + cg * 16 + (ln & 15);
        *reinterpret_cast<half8*>(lds + (size_t)flat * 8) =
            ld8(slot + (size_t)col * HID + kb * 32 + (ln >> 4) * 8);
    }
    __syncthreads();

    const int colh = cg * 16 + lr;
    const float bh = bias[d * NH2 + colh];
    const float bg = bias[d * NH2 + HID + colh];
    const int* __restrict__ pc = cnt + (((d + 3) & 3) * 32);  // prev depth's line
    int* __restrict__ myc = cnt + d * 32;

    for (int t = 0; t < SEQ; ++t) {
        const int gp = t * 4 + d;

        // prefetch hg0 for this t (d==0 only) -- independent of the barrier
        float pre_h[4], pre_g[4];
        if (d == 0) {
#pragma unroll
            for (int i = 0; i < 4; ++i) {
                const int gr = m0 + (lane >> 4) * 4 + i;
                const size_t hb = (size_t)(t * NB + gr) * NH2 + colh;
                pre_h[i] = (float)hg0[hb];
                pre_g[i] = (float)hg0[hb + HID];
            }
            __asm__ __volatile__("" :: "v"(pre_h[0]), "v"(pre_h[1]), "v"(pre_h[2]),
                                 "v"(pre_h[3]), "v"(pre_g[0]), "v"(pre_g[1]),
                                 "v"(pre_g[2]), "v"(pre_g[3]));
        }

        // wait for previous phase: 64 arrivals on the prev-depth counter
        const int target = (d == 0) ? 64 * t : 64 * (t + 1);
        if (tid == 0) {
            while (__hip_atomic_load(pc, __ATOMIC_RELAXED, __HIP_MEMORY_SCOPE_AGENT) <
                   target) {
            }
        }
        __syncthreads();
        // acquire: invalidate stale L1/XCD-L2 lines of the mirror/carry
        __builtin_amdgcn_fence(__ATOMIC_ACQUIRE, "agent");

        // issue carry loads early; latency hides under the GEMM
        float sold[4];
#pragma unroll
        for (int i = 0; i < 4; ++i) {
            const int gr = m0 + (lane >> 4) * 4 + i;
            sold[i] = __hip_atomic_load(carry + (size_t)gr * HID + colh,
                                        __ATOMIC_RELAXED, __HIP_MEMORY_SCOPE_AGENT);
        }
        __asm__ __volatile__("" :: "v"(sold[0]), "v"(sold[1]), "v"(sold[2]),
                             "v"(sold[3]));

        const _Float16* __restrict__ mr = (gp & 1) ? mirB : mirA;
        const _Float16* __restrict__ arow = mr + (size_t)(m0 + lr) * HID + kofs;
        float4v acch = {0.f, 0.f, 0.f, 0.f};
        float4v accg = {0.f, 0.f, 0.f, 0.f};
#pragma unroll 8
        for (int kb = 0; kb < 32; ++kb) {
            half8 a = ld8(arow + kb * 32);  // plain cached load (post-acquire)
            half8 bhf = *reinterpret_cast<const half8*>(lds + (size_t)(kb * 64 + lane) * 8);
            half8 bgf =
                *reinterpret_cast<const half8*>(lds + (size_t)((32 + kb) * 64 + lane) * 8);
            acch = __builtin_amdgcn_mfma_f32_16x16x32_f16(a, bhf, acch, 0, 0, 0);
            accg = __builtin_amdgcn_mfma_f32_16x16x32_f16(a, bgf, accg, 0, 0, 0);
        }

        _Float16* __restrict__ mw = ((gp + 1) & 1) ? mirB : mirA;
#pragma unroll
        for (int i = 0; i < 4; ++i) {
            const int gr = m0 + (lane >> 4) * 4 + i;
            const size_t idx = (size_t)gr * HID + colh;
            float ah = acch[i] + bh;
            float ag = accg[i] + bg;
            if (d == 0) {
                ah += pre_h[i];
                ag += pre_g[i];
            }
            // fast tanh/sigmoid via hw exp; |err| ~1e-6, fp16 state dominates
            const float hv = 1.0f - __fdividef(2.0f, __expf(2.0f * ah) + 1.0f);
            const float gv = __fdividef(1.0f, 1.0f + __expf(-ag));
            const float sn = hv * gv + sold[i] * (1.f - gv);
            __hip_atomic_store(carry + idx, sn, __ATOMIC_RELAXED,
                               __HIP_MEMORY_SCOPE_AGENT);
            const unsigned short mine = __builtin_bit_cast(unsigned short, (_Float16)sn);
            const unsigned short oth = (unsigned short)__shfl_xor((int)mine, 1, 64);
            const uint32_t pk = (uint32_t)mine | ((uint32_t)oth << 16);
            if ((lane & 1) == 0) {
                __hip_atomic_store(reinterpret_cast<uint32_t*>(mw + idx), pk,
                                   __ATOMIC_RELAXED, __HIP_MEMORY_SCOPE_AGENT);
            }
            if (d == 3) {
                if (sseq) {
                    if ((lane & 1) == 0)
                        *reinterpret_cast<uint32_t*>(sseq + (size_t)t * SBUF + idx) = pk;
                } else {
                    outp[(size_t)t * SBUF + idx] = sn;
                }
                if (t == SEQ - 1) fout[idx] = sn;
            }
        }
        __syncthreads();  // drains all 4 waves' stores (vmcnt 0) before arrive
        if (tid == 0)
            __hip_atomic_fetch_add(myc, 1, __ATOMIC_RELAXED, __HIP_MEMORY_SCOPE_AGENT);
    }
}

extern "C" void kernel_launch(void* const* d_in, const int* in_sizes, int n_in,
                              void* d_out, int out_size, void* d_ws, size_t ws_size,
                              hipStream_t stream) {
    (void)in_sizes; (void)n_in; (void)out_size; (void)ws_size;
    const float* x     = (const float*)d_in[0];
    const float* state = (const float*)d_in[1];
    const float* w_in  = (const float*)d_in[2];
    const float* w_h   = (const float*)d_in[3];
    const float* b_h   = (const float*)d_in[4];
    float* out = (float*)d_out;
    char* ws = (char*)d_ws;
    _Float16* Wt   = (_Float16*)ws;
    _Float16* HG0  = (_Float16*)(ws + OFF_HG0);
    _Float16* Sseq = (_Float16*)(ws + OFF_SSEQ);
    _Float16* mir0a = (_Float16*)(ws + OFF_MIR);
    _Float16* mir0b = mir0a + SBUF;
    _Float16* mir1a = mir0b + SBUF;
    _Float16* mir1b = mir1a + SBUF;
    float* car0 = (float*)(ws + OFF_CAR);
    float* car1 = car0 + SBUF;
    int* cnts = (int*)(ws + OFF_CNT);   // layer0: cnts[0..127], layer1: +128

    (void)hipFuncSetAttribute((const void*)rhn_scan,
                              hipFuncAttributeMaxDynamicSharedMemorySize, 65536);

    wprep<<<10 * 64 * 32, 256, 0, stream>>>(w_in, w_h, Wt);
    sinit2<<<(SBUF + 255) / 256, 256, 0, stream>>>(state, mir0a, car0, mir1a, car1, cnts);
    // HG0_l0 = x @ w_in[0]
    gemm_proj<false><<<512 * 32, 256, 0, stream>>>((const void*)x, Wt + 0 * WSLOT, HG0);
    // scan layer 0 (writes Sseq fp16, fout[0])
    rhn_scan<<<256, 256, 65536, stream>>>(Wt, 1, b_h, HG0, mir0a, mir0b, car0, cnts,
                                          Sseq, (float*)nullptr,
                                          out + (size_t)SEQ * SBUF);
    // HG0_l1 = Sseq @ w_in[1]  (reuse HG0 buffer)
    gemm_proj<true><<<512 * 32, 256, 0, stream>>>((const void*)Sseq, Wt + 5 * WSLOT, HG0);
    // scan layer 1 (writes out[t], fout[1])
    rhn_scan<<<256, 256, 65536, stream>>>(Wt, 6, b_h + (size_t)ND * NH2, HG0, mir1a,
                                          mir1b, car1, cnts + 128, (_Float16*)nullptr,
                                          out, out + (size_t)SEQ * SBUF + SBUF);
}

// Round 2
// 38639.661 us; speedup vs baseline: 1.7079x; 1.1887x over previous
//
#include <hip/hip_runtime.h>
#include <math.h>
#include <stdint.h>

// RHN round 4: flag-array barrier (no RMW pile-up) + two-layer pipelining.
//  - One fused persistent kernel: 256 WGs (1/CU, 128 KB LDS = both layers'
//    weight slices). Beat b: stage d computes layer0 t=b and layer1 t=b-1 as
//    interleaved MFMA chains. 513 beats x 4 phases vs 2x512x4 before.
//  - Sync: per-stage 64-int flag arrays; producers STORE beat+1 (no
//    fetch_add); consumers poll 64 flags with one wave-wide load + __all.
//  - Layer-1 d0 fuses the input projection (Sseq(t-1) @ w_in[1]) as
//    extended-K, streaming the w_in[1] slice from MALL (no LDS room).
//  - Entry barrier removed (all waves poll; end-of-beat barrier preserves
//    the WG-serial invariant). Acquire fence before cached mirror reads.

#define SEQ 512
#define NB 64
#define HID 1024
#define NH2 2048
#define NL 2
#define ND 4
#define SBUF (NB * HID)                    // 65536
#define WSLOT ((size_t)NH2 * (size_t)HID)  // 2097152 elems per slot
#define MROWS (SEQ * NB)                   // 32768

typedef _Float16 half8 __attribute__((ext_vector_type(8)));
typedef float float4v __attribute__((ext_vector_type(4)));

// ---- workspace layout (bytes) ----
#define OFF_HG0 ((size_t)10 * WSLOT * 2)                 // Wt = 40MB
#define OFF_SSEQ (OFF_HG0 + (size_t)MROWS * NH2 * 2)     // HG0 = 128MB
#define OFF_MIR (OFF_SSEQ + (size_t)MROWS * HID * 2)     // Sseq = 64MB
#define OFF_CAR (OFF_MIR + (size_t)4 * SBUF * 2)         // 4 mirrors fp16
#define OFF_CNT (OFF_CAR + (size_t)2 * SBUF * 4)         // 2 carries fp32
// flags: 4 stages x 64 ints = 1KB

__device__ __forceinline__ half8 ld8(const _Float16* p) {
    return *reinterpret_cast<const half8*>(p);
}

__device__ __forceinline__ half8 cvt8(const float* p) {
    const float4v a = *reinterpret_cast<const float4v*>(p);
    const float4v b = *reinterpret_cast<const float4v*>(p + 4);
    half8 r;
    r[0] = (_Float16)a[0]; r[1] = (_Float16)a[1];
    r[2] = (_Float16)a[2]; r[3] = (_Float16)a[3];
    r[4] = (_Float16)b[0]; r[5] = (_Float16)b[1];
    r[6] = (_Float16)b[2]; r[7] = (_Float16)b[3];
    return r;
}

// ---- prep: transpose+convert weights to fp16 [n][k] ----
// slots per layer l: l*5+0 = w_in[l]^T ; l*5+1..4 = w_h[l][d]^T
__global__ __launch_bounds__(256) void wprep(const float* __restrict__ w_in,
                                             const float* __restrict__ w_h,
                                             _Float16* __restrict__ Wt) {
    const int bid = (int)blockIdx.x;
    const int tk = bid & 31;
    const int tn = (bid >> 5) & 63;
    const int slot = bid >> 11;  // 0..9
    const int l = slot / 5;
    const int j = slot - l * 5;
    const float* __restrict__ src = (j == 0)
        ? (w_in + (size_t)l * WSLOT)
        : (w_h + (size_t)(l * ND + (j - 1)) * WSLOT);
    __shared__ float tile[32][33];
    const int tx = (int)(threadIdx.x & 31u);
    const int ty = (int)(threadIdx.x >> 5);
    const int n = tn * 32 + tx;
#pragma unroll
    for (int r = 0; r < 4; ++r) {
        const int k = tk * 32 + ty + r * 8;
        tile[ty + r * 8][tx] = src[(size_t)k * NH2 + n];
    }
    __syncthreads();
    _Float16* __restrict__ dst = Wt + (size_t)slot * WSLOT;
#pragma unroll
    for (int r = 0; r < 4; ++r) {
        const int nn = tn * 32 + ty + r * 8;
        const int kk = tk * 32 + tx;
        dst[(size_t)nn * HID + kk] = (_Float16)tile[tx][ty + r * 8];
    }
}

// ---- prep: init mirrors (fp16) + carries (fp32) + flags ----
__global__ void sinit2(const float* __restrict__ state, _Float16* __restrict__ mir0,
                       float* __restrict__ car0, _Float16* __restrict__ mir1,
                       float* __restrict__ car1, int* __restrict__ cnts) {
    const int i = (int)(blockIdx.x * 256 + threadIdx.x);
    if (i < SBUF) {
        const float v0 = state[i];
        const float v1 = state[SBUF + i];
        mir0[i] = (_Float16)v0; car0[i] = v0;
        mir1[i] = (_Float16)v1; car1[i] = v1;
    }
    if (i < 256) cnts[i] = 0;
}

// ---- bulk input-projection GEMM (layer 0 only): C = x @ w_in0, fp16 out ----
template <bool AF16>
__global__ __launch_bounds__(256) void gemm_proj(const void* __restrict__ Av,
                                                 const _Float16* __restrict__ Bslot,
                                                 _Float16* __restrict__ C) {
    const int bid = (int)blockIdx.x;
    const int nt = bid & 31;    // 32 n-tiles of 64
    const int mt = bid >> 5;    // 512 m-tiles of 64
    const int lane = (int)(threadIdx.x & 63u);
    const int wv = (int)(threadIdx.x >> 6);
    const int lr = lane & 15;
    const int kofs = (lane >> 4) * 8;
    const int m = mt * 64 + wv * 16 + lr;
    float4v acc[4];
#pragma unroll
    for (int i = 0; i < 4; ++i) acc[i] = (float4v){0.f, 0.f, 0.f, 0.f};
#pragma unroll 4
    for (int kb = 0; kb < 32; ++kb) {
        half8 a;
        if (AF16) a = ld8((const _Float16*)Av + (size_t)m * HID + kb * 32 + kofs);
        else      a = cvt8((const float*)Av + (size_t)m * HID + kb * 32 + kofs);
#pragma unroll
        for (int ct = 0; ct < 4; ++ct) {
            const int n = nt * 64 + ct * 16 + lr;
            half8 b = ld8(Bslot + (size_t)n * HID + kb * 32 + kofs);
            acc[ct] = __builtin_amdgcn_mfma_f32_16x16x32_f16(a, b, acc[ct], 0, 0, 0);
        }
    }
#pragma unroll
    for (int ct = 0; ct < 4; ++ct) {
#pragma unroll
        for (int i = 0; i < 4; ++i) {
            const int row = mt * 64 + wv * 16 + (lane >> 4) * 4 + i;
            const int col = nt * 64 + ct * 16 + lr;
            const unsigned short mine =
                __builtin_bit_cast(unsigned short, (_Float16)acc[ct][i]);
            const unsigned short oth = (unsigned short)__shfl_xor((int)mine, 1, 64);
            if ((lane & 1) == 0) {
                const uint32_t pk = (uint32_t)mine | ((uint32_t)oth << 16);
                *reinterpret_cast<uint32_t*>(C + (size_t)row * NH2 + col) = pk;
            }
        }
    }
}

// B-fragment from LDS: [layer][tile][kb][lane] half8
#define WFRAG(lyr, tile, kb)                                                     \
    (*reinterpret_cast<const half8*>(                                            \
        lds + ((size_t)((lyr)*4096 + (tile)*2048 + (kb)*64 + lane)) * 8))

// ---- fused two-layer scan: 513 beats x 4 stage-phases ----
__global__ __launch_bounds__(256) void rhn_fused(
    const _Float16* __restrict__ Wt,
    const float* __restrict__ bias,      // b_h : [NL][ND][NH2]
    const _Float16* __restrict__ hg0,    // [MROWS][NH2] x@w_in0
    _Float16* __restrict__ sseq,         // [SEQ][NB][HID] layer0 outputs fp16
    _Float16* __restrict__ m0a, _Float16* __restrict__ m0b,
    _Float16* __restrict__ m1a, _Float16* __restrict__ m1b,
    float* __restrict__ car0, float* __restrict__ car1,
    int* __restrict__ flags,             // [4][64]
    float* __restrict__ outp,            // [SEQ][NB][HID] fp32 (layer1 out)
    float* __restrict__ fout0, float* __restrict__ fout1) {
    extern __shared__ _Float16 lds[];    // [2 layers][2 tiles][32 kb][64][8] =128KB
    const int wg = (int)blockIdx.x;
    const int d = wg >> 6;
    const int cg = wg & 63;
    const int tid = (int)threadIdx.x;
    const int lane = tid & 63;
    const int m0 = (tid >> 6) * 16;
    const int lr = lane & 15;
    const int kofs = (lane >> 4) * 8;
    const bool isD0 = (d == 0);

    // fill LDS: both layers' weight slices for this (d, cg)
    for (int i = 0; i < 32; ++i) {
        const int flat = i * 256 + tid;       // 0..8191
        const int lyr = flat >> 12;
        const int rem = flat & 4095;
        const int tile = rem >> 11;
        const int kb = (rem >> 6) & 31;
        const int ln = rem & 63;
        const _Float16* __restrict__ slot =
            Wt + (size_t)((lyr ? 6 : 1) + d) * WSLOT;
        const int col = tile * HID + cg * 16 + (ln & 15);
        *reinterpret_cast<half8*>(lds + (size_t)flat * 8) =
            ld8(slot + (size_t)col * HID + kb * 32 + (ln >> 4) * 8);
    }
    __syncthreads();

    const int colh = cg * 16 + lr;
    const float bh0 = bias[d * NH2 + colh];
    const float bg0 = bias[d * NH2 + HID + colh];
    const float bh1 = bias[(ND + d) * NH2 + colh];
    const float bg1 = bias[(ND + d) * NH2 + HID + colh];
    const int prev = (d + 3) & 3;
    int* __restrict__ pfl = flags + prev * 64 + lane;
    int* __restrict__ myf = flags + d * 64 + cg;
    // w_in[1] streamed fragment base (stage 0 only)
    const _Float16* __restrict__ winp =
        Wt + (size_t)5 * WSLOT + (size_t)(cg * 16 + lr) * HID + kofs;
    const size_t WGOFF = (size_t)HID * HID;  // +HID cols in [n][k] layout

    for (int b = 0; b <= SEQ; ++b) {
        const bool doL0 = (b < SEQ);
        const bool doL1 = (b > 0);
        const int t1 = b - 1;

        // hg0 prefetch (stage0/layer0) -- read-only, independent of barrier
        float pre_h[4], pre_g[4];
        if (isD0 && doL0) {
#pragma unroll
            for (int i = 0; i < 4; ++i) {
                const int gr = m0 + (lane >> 4) * 4 + i;
                const size_t hb = (size_t)(b * NB + gr) * NH2 + colh;
                pre_h[i] = (float)hg0[hb];
                pre_g[i] = (float)hg0[hb + HID];
            }
            __asm__ __volatile__("" :: "v"(pre_h[0]), "v"(pre_h[1]), "v"(pre_h[2]),
                                 "v"(pre_h[3]), "v"(pre_g[0]), "v"(pre_g[1]),
                                 "v"(pre_g[2]), "v"(pre_g[3]));
        }

        // wait: all 64 prev-stage WGs reached this beat (wave-wide flag read)
        const int target = isD0 ? b : b + 1;
        if (target > 0) {
            while (true) {
                const int v =
                    __hip_atomic_load(pfl, __ATOMIC_RELAXED, __HIP_MEMORY_SCOPE_AGENT);
                if (__all(v >= target)) break;
            }
        }
        // acquire: invalidate stale L1/L2 so mirrors/sseq/carry read fresh
        __builtin_amdgcn_fence(__ATOMIC_ACQUIRE, "agent");

        // early carry loads; latency hides under the GEMMs
        float sold0[4], sold1[4];
        if (doL0) {
#pragma unroll
            for (int i = 0; i < 4; ++i) {
                const int gr = m0 + (lane >> 4) * 4 + i;
                sold0[i] = __hip_atomic_load(car0 + (size_t)gr * HID + colh,
                                             __ATOMIC_RELAXED, __HIP_MEMORY_SCOPE_AGENT);
            }
            __asm__ __volatile__("" :: "v"(sold0[0]), "v"(sold0[1]), "v"(sold0[2]),
                                 "v"(sold0[3]));
        }
        if (doL1) {
#pragma unroll
            for (int i = 0; i < 4; ++i) {
                const int gr = m0 + (lane >> 4) * 4 + i;
                sold1[i] = __hip_atomic_load(car1 + (size_t)gr * HID + colh,
                                             __ATOMIC_RELAXED, __HIP_MEMORY_SCOPE_AGENT);
            }
            __asm__ __volatile__("" :: "v"(sold1[0]), "v"(sold1[1]), "v"(sold1[2]),
                                 "v"(sold1[3]));
        }

        const int gp0 = b * 4 + d;
        const int gp1 = t1 * 4 + d;
        const _Float16* __restrict__ a0p =
            ((gp0 & 1) ? m0b : m0a) + (size_t)(m0 + lr) * HID + kofs;
        const _Float16* __restrict__ a1p =
            ((gp1 & 1) ? m1b : m1a) + (size_t)(m0 + lr) * HID + kofs;
        const _Float16* __restrict__ a2p =
            sseq + ((size_t)t1 * NB + (m0 + lr)) * HID + kofs;

        float4v acch0 = {0.f, 0.f, 0.f, 0.f}, accg0 = {0.f, 0.f, 0.f, 0.f};
        float4v acch1 = {0.f, 0.f, 0.f, 0.f}, accg1 = {0.f, 0.f, 0.f, 0.f};

        if (doL0 && doL1) {
            if (isD0) {
#pragma unroll 4
                for (int kb = 0; kb < 32; ++kb) {
                    half8 a0 = ld8(a0p + kb * 32);
                    half8 a1 = ld8(a1p + kb * 32);
                    half8 a2 = ld8(a2p + kb * 32);
                    acch0 = __builtin_amdgcn_mfma_f32_16x16x32_f16(a0, WFRAG(0, 0, kb), acch0, 0, 0, 0);
                    accg0 = __builtin_amdgcn_mfma_f32_16x16x32_f16(a0, WFRAG(0, 1, kb), accg0, 0, 0, 0);
                    acch1 = __builtin_amdgcn_mfma_f32_16x16x32_f16(a1, WFRAG(1, 0, kb), acch1, 0, 0, 0);
                    accg1 = __builtin_amdgcn_mfma_f32_16x16x32_f16(a1, WFRAG(1, 1, kb), accg1, 0, 0, 0);
                    acch1 = __builtin_amdgcn_mfma_f32_16x16x32_f16(a2, ld8(winp + (size_t)kb * 32), acch1, 0, 0, 0);
                    accg1 = __builtin_amdgcn_mfma_f32_16x16x32_f16(a2, ld8(winp + WGOFF + kb * 32), accg1, 0, 0, 0);
                }
            } else {
#pragma unroll 8
                for (int kb = 0; kb < 32; ++kb) {
                    half8 a0 = ld8(a0p + kb * 32);
                    half8 a1 = ld8(a1p + kb * 32);
                    acch0 = __builtin_amdgcn_mfma_f32_16x16x32_f16(a0, WFRAG(0, 0, kb), acch0, 0, 0, 0);
                    accg0 = __builtin_amdgcn_mfma_f32_16x16x32_f16(a0, WFRAG(0, 1, kb), accg0, 0, 0, 0);
                    acch1 = __builtin_amdgcn_mfma_f32_16x16x32_f16(a1, WFRAG(1, 0, kb), acch1, 0, 0, 0);
                    accg1 = __builtin_amdgcn_mfma_f32_16x16x32_f16(a1, WFRAG(1, 1, kb), accg1, 0, 0, 0);
                }
            }
        } else if (doL0) {  // b == 0
#pragma unroll 8
            for (int kb = 0; kb < 32; ++kb) {
                half8 a0 = ld8(a0p + kb * 32);
                acch0 = __builtin_amdgcn_mfma_f32_16x16x32_f16(a0, WFRAG(0, 0, kb), acch0, 0, 0, 0);
                accg0 = __builtin_amdgcn_mfma_f32_16x16x32_f16(a0, WFRAG(0, 1, kb), accg0, 0, 0, 0);
            }
        } else {  // b == SEQ : layer1 only
            if (isD0) {
#pragma unroll 8
                for (int kb = 0; kb < 32; ++kb) {
                    half8 a1 = ld8(a1p + kb * 32);
                    half8 a2 = ld8(a2p + kb * 32);
                    acch1 = __builtin_amdgcn_mfma_f32_16x16x32_f16(a1, WFRAG(1, 0, kb), acch1, 0, 0, 0);
                    accg1 = __builtin_amdgcn_mfma_f32_16x16x32_f16(a1, WFRAG(1, 1, kb), accg1, 0, 0, 0);
                    acch1 = __builtin_amdgcn_mfma_f32_16x16x32_f16(a2, ld8(winp + (size_t)kb * 32), acch1, 0, 0, 0);
                    accg1 = __builtin_amdgcn_mfma_f32_16x16x32_f16(a2, ld8(winp + WGOFF + kb * 32), accg1, 0, 0, 0);
                }
            } else {
#pragma unroll 8
                for (int kb = 0; kb < 32; ++kb) {
                    half8 a1 = ld8(a1p + kb * 32);
                    acch1 = __builtin_amdgcn_mfma_f32_16x16x32_f16(a1, WFRAG(1, 0, kb), acch1, 0, 0, 0);
                    accg1 = __builtin_amdgcn_mfma_f32_16x16x32_f16(a1, WFRAG(1, 1, kb), accg1, 0, 0, 0);
                }
            }
        }

        // ---- epilogue layer 0 (t = b) ----
        if (doL0) {
            _Float16* __restrict__ mw = ((gp0 + 1) & 1) ? m0b : m0a;
#pragma unroll
            for (int i = 0; i < 4; ++i) {
                const int gr = m0 + (lane >> 4) * 4 + i;
                const size_t idx = (size_t)gr * HID + colh;
                float ah = acch0[i] + bh0;
                float ag = accg0[i] + bg0;
                if (isD0) { ah += pre_h[i]; ag += pre_g[i]; }
                const float hv = 1.0f - __fdividef(2.0f, __expf(2.0f * ah) + 1.0f);
                const float gv = __fdividef(1.0f, 1.0f + __expf(-ag));
                const float sn = hv * gv + sold0[i] * (1.f - gv);
                __hip_atomic_store(car0 + idx, sn, __ATOMIC_RELAXED,
                                   __HIP_MEMORY_SCOPE_AGENT);
                const unsigned short mine = __builtin_bit_cast(unsigned short, (_Float16)sn);
                const unsigned short oth = (unsigned short)__shfl_xor((int)mine, 1, 64);
                const uint32_t pk = (uint32_t)mine | ((uint32_t)oth << 16);
                if ((lane & 1) == 0) {
                    __hip_atomic_store(reinterpret_cast<uint32_t*>(mw + idx), pk,
                                       __ATOMIC_RELAXED, __HIP_MEMORY_SCOPE_AGENT);
                    if (d == 3) {
                        __hip_atomic_store(
                            reinterpret_cast<uint32_t*>(sseq + (size_t)b * SBUF + idx),
                            pk, __ATOMIC_RELAXED, __HIP_MEMORY_SCOPE_AGENT);
                    }
                }
                if (d == 3 && b == SEQ - 1) fout0[idx] = sn;
            }
        }
        // ---- epilogue layer 1 (t = b-1) ----
        if (doL1) {
            _Float16* __restrict__ mw = ((gp1 + 1) & 1) ? m1b : m1a;
#pragma unroll
            for (int i = 0; i < 4; ++i) {
                const int gr = m0 + (lane >> 4) * 4 + i;
                const size_t idx = (size_t)gr * HID + colh;
                const float ah = acch1[i] + bh1;
                const float ag = accg1[i] + bg1;
                const float hv = 1.0f - __fdividef(2.0f, __expf(2.0f * ah) + 1.0f);
                const float gv = __fdividef(1.0f, 1.0f + __expf(-ag));
                const float sn = hv * gv + sold1[i] * (1.f - gv);
                __hip_atomic_store(car1 + idx, sn, __ATOMIC_RELAXED,
                                   __HIP_MEMORY_SCOPE_AGENT);
                const unsigned short mine = __builtin_bit_cast(unsigned short, (_Float16)sn);
                const unsigned short oth = (unsigned short)__shfl_xor((int)mine, 1, 64);
                const uint32_t pk = (uint32_t)mine | ((uint32_t)oth << 16);
                if ((lane & 1) == 0) {
                    __hip_atomic_store(reinterpret_cast<uint32_t*>(mw + idx), pk,
                                       __ATOMIC_RELAXED, __HIP_MEMORY_SCOPE_AGENT);
                }
                if (d == 3) {
                    outp[(size_t)t1 * SBUF + idx] = sn;
                    if (t1 == SEQ - 1) fout1[idx] = sn;
                }
            }
        }
        __syncthreads();  // all 4 waves drained (vmcnt 0) before arrival flag
        if (tid == 0)
            __hip_atomic_store(myf, b + 1, __ATOMIC_RELAXED, __HIP_MEMORY_SCOPE_AGENT);
    }
}

extern "C" void kernel_launch(void* const* d_in, const int* in_sizes, int n_in,
                              void* d_out, int out_size, void* d_ws, size_t ws_size,
                              hipStream_t stream) {
    (void)in_sizes; (void)n_in; (void)out_size; (void)ws_size;
    const float* x     = (const float*)d_in[0];
    const float* state = (const float*)d_in[1];
    const float* w_in  = (const float*)d_in[2];
    const float* w_h   = (const float*)d_in[3];
    const float* b_h   = (const float*)d_in[4];
    float* out = (float*)d_out;
    char* ws = (char*)d_ws;
    _Float16* Wt   = (_Float16*)ws;
    _Float16* HG0  = (_Float16*)(ws + OFF_HG0);
    _Float16* Sseq = (_Float16*)(ws + OFF_SSEQ);
    _Float16* mir0a = (_Float16*)(ws + OFF_MIR);
    _Float16* mir0b = mir0a + SBUF;
    _Float16* mir1a = mir0b + SBUF;
    _Float16* mir1b = mir1a + SBUF;
    float* car0 = (float*)(ws + OFF_CAR);
    float* car1 = car0 + SBUF;
    int* flags = (int*)(ws + OFF_CNT);

    (void)hipFuncSetAttribute((const void*)rhn_fused,
                              hipFuncAttributeMaxDynamicSharedMemorySize, 131072);

    wprep<<<10 * 64 * 32, 256, 0, stream>>>(w_in, w_h, Wt);
    sinit2<<<(SBUF + 255) / 256, 256, 0, stream>>>(state, mir0a, car0, mir1a, car1, flags);
    // HG0 = x @ w_in[0]
    gemm_proj<false><<<512 * 32, 256, 0, stream>>>((const void*)x, Wt + 0 * WSLOT, HG0);
    // fused two-layer pipelined scan
    rhn_fused<<<256, 256, 131072, stream>>>(
        Wt, b_h, HG0, Sseq, mir0a, mir0b, mir1a, mir1b, car0, car1, flags,
        out, out + (size_t)SEQ * SBUF, out + (size_t)SEQ * SBUF + SBUF);
}

// Round 3
// 37760.803 us; speedup vs baseline: 1.7477x; 1.0233x over previous
//
#include <hip/hip_runtime.h>
#include <math.h>
#include <stdint.h>

// RHN round 5: fix the poll-contention regression from r4.
//  - Arrival: per-stage 64-int flag arrays, producers STORE beat+1 (no RMW).
//  - Wait: ONLY wave 0 polls (one coalesced 64-lane agent load + __all);
//    waves 1-3 park in __syncthreads (no spin traffic). r4 had all 1024
//    waves spinning at MALL -> 18us/phase; r3's single-poller discipline
//    gave 10us with an RMW barrier. This combines both fixes.
//  - Dead-end outputs (outp/fout) stored AFTER the arrival flag: their HBM
//    ack drains during the next poll, not inside the pre-flag barrier.
//  - Rest identical to r4: fused two-layer beat (513 beats x 4 stages),
//    128KB LDS weights, fence+cached mirror reads, hg0 prefetch, early
//    carry loads, streamed w_in[1] at stage 0.

#define SEQ 512
#define NB 64
#define HID 1024
#define NH2 2048
#define NL 2
#define ND 4
#define SBUF (NB * HID)                    // 65536
#define WSLOT ((size_t)NH2 * (size_t)HID)  // 2097152 elems per slot
#define MROWS (SEQ * NB)                   // 32768

typedef _Float16 half8 __attribute__((ext_vector_type(8)));
typedef float float4v __attribute__((ext_vector_type(4)));

// ---- workspace layout (bytes) ----
#define OFF_HG0 ((size_t)10 * WSLOT * 2)                 // Wt = 40MB
#define OFF_SSEQ (OFF_HG0 + (size_t)MROWS * NH2 * 2)     // HG0 = 128MB
#define OFF_MIR (OFF_SSEQ + (size_t)MROWS * HID * 2)     // Sseq = 64MB
#define OFF_CAR (OFF_MIR + (size_t)4 * SBUF * 2)         // 4 mirrors fp16
#define OFF_CNT (OFF_CAR + (size_t)2 * SBUF * 4)         // 2 carries fp32
// flags: 4 stages x 64 ints = 1KB

__device__ __forceinline__ half8 ld8(const _Float16* p) {
    return *reinterpret_cast<const half8*>(p);
}

__device__ __forceinline__ half8 cvt8(const float* p) {
    const float4v a = *reinterpret_cast<const float4v*>(p);
    const float4v b = *reinterpret_cast<const float4v*>(p + 4);
    half8 r;
    r[0] = (_Float16)a[0]; r[1] = (_Float16)a[1];
    r[2] = (_Float16)a[2]; r[3] = (_Float16)a[3];
    r[4] = (_Float16)b[0]; r[5] = (_Float16)b[1];
    r[6] = (_Float16)b[2]; r[7] = (_Float16)b[3];
    return r;
}

// ---- prep: transpose+convert weights to fp16 [n][k] ----
// slots per layer l: l*5+0 = w_in[l]^T ; l*5+1..4 = w_h[l][d]^T
__global__ __launch_bounds__(256) void wprep(const float* __restrict__ w_in,
                                             const float* __restrict__ w_h,
                                             _Float16* __restrict__ Wt) {
    const int bid = (int)blockIdx.x;
    const int tk = bid & 31;
    const int tn = (bid >> 5) & 63;
    const int slot = bid >> 11;  // 0..9
    const int l = slot / 5;
    const int j = slot - l * 5;
    const float* __restrict__ src = (j == 0)
        ? (w_in + (size_t)l * WSLOT)
        : (w_h + (size_t)(l * ND + (j - 1)) * WSLOT);
    __shared__ float tile[32][33];
    const int tx = (int)(threadIdx.x & 31u);
    const int ty = (int)(threadIdx.x >> 5);
    const int n = tn * 32 + tx;
#pragma unroll
    for (int r = 0; r < 4; ++r) {
        const int k = tk * 32 + ty + r * 8;
        tile[ty + r * 8][tx] = src[(size_t)k * NH2 + n];
    }
    __syncthreads();
    _Float16* __restrict__ dst = Wt + (size_t)slot * WSLOT;
#pragma unroll
    for (int r = 0; r < 4; ++r) {
        const int nn = tn * 32 + ty + r * 8;
        const int kk = tk * 32 + tx;
        dst[(size_t)nn * HID + kk] = (_Float16)tile[tx][ty + r * 8];
    }
}

// ---- prep: init mirrors (fp16) + carries (fp32) + flags ----
__global__ void sinit2(const float* __restrict__ state, _Float16* __restrict__ mir0,
                       float* __restrict__ car0, _Float16* __restrict__ mir1,
                       float* __restrict__ car1, int* __restrict__ cnts) {
    const int i = (int)(blockIdx.x * 256 + threadIdx.x);
    if (i < SBUF) {
        const float v0 = state[i];
        const float v1 = state[SBUF + i];
        mir0[i] = (_Float16)v0; car0[i] = v0;
        mir1[i] = (_Float16)v1; car1[i] = v1;
    }
    if (i < 256) cnts[i] = 0;
}

// ---- bulk input-projection GEMM (layer 0 only): C = x @ w_in0, fp16 out ----
template <bool AF16>
__global__ __launch_bounds__(256) void gemm_proj(const void* __restrict__ Av,
                                                 const _Float16* __restrict__ Bslot,
                                                 _Float16* __restrict__ C) {
    const int bid = (int)blockIdx.x;
    const int nt = bid & 31;    // 32 n-tiles of 64
    const int mt = bid >> 5;    // 512 m-tiles of 64
    const int lane = (int)(threadIdx.x & 63u);
    const int wv = (int)(threadIdx.x >> 6);
    const int lr = lane & 15;
    const int kofs = (lane >> 4) * 8;
    const int m = mt * 64 + wv * 16 + lr;
    float4v acc[4];
#pragma unroll
    for (int i = 0; i < 4; ++i) acc[i] = (float4v){0.f, 0.f, 0.f, 0.f};
#pragma unroll 4
    for (int kb = 0; kb < 32; ++kb) {
        half8 a;
        if (AF16) a = ld8((const _Float16*)Av + (size_t)m * HID + kb * 32 + kofs);
        else      a = cvt8((const float*)Av + (size_t)m * HID + kb * 32 + kofs);
#pragma unroll
        for (int ct = 0; ct < 4; ++ct) {
            const int n = nt * 64 + ct * 16 + lr;
            half8 b = ld8(Bslot + (size_t)n * HID + kb * 32 + kofs);
            acc[ct] = __builtin_amdgcn_mfma_f32_16x16x32_f16(a, b, acc[ct], 0, 0, 0);
        }
    }
#pragma unroll
    for (int ct = 0; ct < 4; ++ct) {
#pragma unroll
        for (int i = 0; i < 4; ++i) {
            const int row = mt * 64 + wv * 16 + (lane >> 4) * 4 + i;
            const int col = nt * 64 + ct * 16 + lr;
            const unsigned short mine =
                __builtin_bit_cast(unsigned short, (_Float16)acc[ct][i]);
            const unsigned short oth = (unsigned short)__shfl_xor((int)mine, 1, 64);
            if ((lane & 1) == 0) {
                const uint32_t pk = (uint32_t)mine | ((uint32_t)oth << 16);
                *reinterpret_cast<uint32_t*>(C + (size_t)row * NH2 + col) = pk;
            }
        }
    }
}

// B-fragment from LDS: [layer][tile][kb][lane] half8
#define WFRAG(lyr, tile, kb)                                                     \
    (*reinterpret_cast<const half8*>(                                            \
        lds + ((size_t)((lyr)*4096 + (tile)*2048 + (kb)*64 + lane)) * 8))

// ---- fused two-layer scan: 513 beats x 4 stage-phases ----
__global__ __launch_bounds__(256) void rhn_fused(
    const _Float16* __restrict__ Wt,
    const float* __restrict__ bias,      // b_h : [NL][ND][NH2]
    const _Float16* __restrict__ hg0,    // [MROWS][NH2] x@w_in0
    _Float16* __restrict__ sseq,         // [SEQ][NB][HID] layer0 outputs fp16
    _Float16* __restrict__ m0a, _Float16* __restrict__ m0b,
    _Float16* __restrict__ m1a, _Float16* __restrict__ m1b,
    float* __restrict__ car0, float* __restrict__ car1,
    int* __restrict__ flags,             // [4][64]
    float* __restrict__ outp,            // [SEQ][NB][HID] fp32 (layer1 out)
    float* __restrict__ fout0, float* __restrict__ fout1) {
    extern __shared__ _Float16 lds[];    // [2 layers][2 tiles][32 kb][64][8] =128KB
    const int wg = (int)blockIdx.x;
    const int d = wg >> 6;
    const int cg = wg & 63;
    const int tid = (int)threadIdx.x;
    const int lane = tid & 63;
    const int m0 = (tid >> 6) * 16;
    const int lr = lane & 15;
    const int kofs = (lane >> 4) * 8;
    const bool isD0 = (d == 0);

    // fill LDS: both layers' weight slices for this (d, cg)
    for (int i = 0; i < 32; ++i) {
        const int flat = i * 256 + tid;       // 0..8191
        const int lyr = flat >> 12;
        const int rem = flat & 4095;
        const int tile = rem >> 11;
        const int kb = (rem >> 6) & 31;
        const int ln = rem & 63;
        const _Float16* __restrict__ slot =
            Wt + (size_t)((lyr ? 6 : 1) + d) * WSLOT;
        const int col = tile * HID + cg * 16 + (ln & 15);
        *reinterpret_cast<half8*>(lds + (size_t)flat * 8) =
            ld8(slot + (size_t)col * HID + kb * 32 + (ln >> 4) * 8);
    }
    __syncthreads();

    const int colh = cg * 16 + lr;
    const float bh0 = bias[d * NH2 + colh];
    const float bg0 = bias[d * NH2 + HID + colh];
    const float bh1 = bias[(ND + d) * NH2 + colh];
    const float bg1 = bias[(ND + d) * NH2 + HID + colh];
    const int prev = (d + 3) & 3;
    int* __restrict__ pfl = flags + prev * 64 + lane;
    int* __restrict__ myf = flags + d * 64 + cg;
    // w_in[1] streamed fragment base (stage 0 only)
    const _Float16* __restrict__ winp =
        Wt + (size_t)5 * WSLOT + (size_t)(cg * 16 + lr) * HID + kofs;
    const size_t WGOFF = (size_t)HID * HID;  // +HID cols in [n][k] layout

    for (int b = 0; b <= SEQ; ++b) {
        const bool doL0 = (b < SEQ);
        const bool doL1 = (b > 0);
        const int t1 = b - 1;

        // hg0 prefetch (stage0/layer0) -- read-only, independent of barrier
        float pre_h[4], pre_g[4];
        if (isD0 && doL0) {
#pragma unroll
            for (int i = 0; i < 4; ++i) {
                const int gr = m0 + (lane >> 4) * 4 + i;
                const size_t hb = (size_t)(b * NB + gr) * NH2 + colh;
                pre_h[i] = (float)hg0[hb];
                pre_g[i] = (float)hg0[hb + HID];
            }
            __asm__ __volatile__("" :: "v"(pre_h[0]), "v"(pre_h[1]), "v"(pre_h[2]),
                                 "v"(pre_h[3]), "v"(pre_g[0]), "v"(pre_g[1]),
                                 "v"(pre_g[2]), "v"(pre_g[3]));
        }

        // wait: ONLY wave 0 polls (coalesced 64-flag load + __all);
        // waves 1-3 park in __syncthreads -- no spin traffic at MALL.
        const int target = isD0 ? b : b + 1;
        if (target > 0) {
            if (tid < 64) {
                while (true) {
                    const int v = __hip_atomic_load(pfl, __ATOMIC_RELAXED,
                                                    __HIP_MEMORY_SCOPE_AGENT);
                    if (__all(v >= target)) break;
                }
            }
            __syncthreads();
        }
        // acquire: invalidate stale L1/L2 so mirrors/sseq/carry read fresh
        __builtin_amdgcn_fence(__ATOMIC_ACQUIRE, "agent");

        // early carry loads; latency hides under the GEMMs
        float sold0[4], sold1[4];
        if (doL0) {
#pragma unroll
            for (int i = 0; i < 4; ++i) {
                const int gr = m0 + (lane >> 4) * 4 + i;
                sold0[i] = __hip_atomic_load(car0 + (size_t)gr * HID + colh,
                                             __ATOMIC_RELAXED, __HIP_MEMORY_SCOPE_AGENT);
            }
            __asm__ __volatile__("" :: "v"(sold0[0]), "v"(sold0[1]), "v"(sold0[2]),
                                 "v"(sold0[3]));
        }
        if (doL1) {
#pragma unroll
            for (int i = 0; i < 4; ++i) {
                const int gr = m0 + (lane >> 4) * 4 + i;
                sold1[i] = __hip_atomic_load(car1 + (size_t)gr * HID + colh,
                                             __ATOMIC_RELAXED, __HIP_MEMORY_SCOPE_AGENT);
            }
            __asm__ __volatile__("" :: "v"(sold1[0]), "v"(sold1[1]), "v"(sold1[2]),
                                 "v"(sold1[3]));
        }

        const int gp0 = b * 4 + d;
        const int gp1 = t1 * 4 + d;
        const _Float16* __restrict__ a0p =
            ((gp0 & 1) ? m0b : m0a) + (size_t)(m0 + lr) * HID + kofs;
        const _Float16* __restrict__ a1p =
            ((gp1 & 1) ? m1b : m1a) + (size_t)(m0 + lr) * HID + kofs;
        const _Float16* __restrict__ a2p =
            sseq + ((size_t)t1 * NB + (m0 + lr)) * HID + kofs;

        float4v acch0 = {0.f, 0.f, 0.f, 0.f}, accg0 = {0.f, 0.f, 0.f, 0.f};
        float4v acch1 = {0.f, 0.f, 0.f, 0.f}, accg1 = {0.f, 0.f, 0.f, 0.f};

        if (doL0 && doL1) {
            if (isD0) {
#pragma unroll 4
                for (int kb = 0; kb < 32; ++kb) {
                    half8 a0 = ld8(a0p + kb * 32);
                    half8 a1 = ld8(a1p + kb * 32);
                    half8 a2 = ld8(a2p + kb * 32);
                    acch0 = __builtin_amdgcn_mfma_f32_16x16x32_f16(a0, WFRAG(0, 0, kb), acch0, 0, 0, 0);
                    accg0 = __builtin_amdgcn_mfma_f32_16x16x32_f16(a0, WFRAG(0, 1, kb), accg0, 0, 0, 0);
                    acch1 = __builtin_amdgcn_mfma_f32_16x16x32_f16(a1, WFRAG(1, 0, kb), acch1, 0, 0, 0);
                    accg1 = __builtin_amdgcn_mfma_f32_16x16x32_f16(a1, WFRAG(1, 1, kb), accg1, 0, 0, 0);
                    acch1 = __builtin_amdgcn_mfma_f32_16x16x32_f16(a2, ld8(winp + (size_t)kb * 32), acch1, 0, 0, 0);
                    accg1 = __builtin_amdgcn_mfma_f32_16x16x32_f16(a2, ld8(winp + WGOFF + kb * 32), accg1, 0, 0, 0);
                }
            } else {
#pragma unroll 8
                for (int kb = 0; kb < 32; ++kb) {
                    half8 a0 = ld8(a0p + kb * 32);
                    half8 a1 = ld8(a1p + kb * 32);
                    acch0 = __builtin_amdgcn_mfma_f32_16x16x32_f16(a0, WFRAG(0, 0, kb), acch0, 0, 0, 0);
                    accg0 = __builtin_amdgcn_mfma_f32_16x16x32_f16(a0, WFRAG(0, 1, kb), accg0, 0, 0, 0);
                    acch1 = __builtin_amdgcn_mfma_f32_16x16x32_f16(a1, WFRAG(1, 0, kb), acch1, 0, 0, 0);
                    accg1 = __builtin_amdgcn_mfma_f32_16x16x32_f16(a1, WFRAG(1, 1, kb), accg1, 0, 0, 0);
                }
            }
        } else if (doL0) {  // b == 0
#pragma unroll 8
            for (int kb = 0; kb < 32; ++kb) {
                half8 a0 = ld8(a0p + kb * 32);
                acch0 = __builtin_amdgcn_mfma_f32_16x16x32_f16(a0, WFRAG(0, 0, kb), acch0, 0, 0, 0);
                accg0 = __builtin_amdgcn_mfma_f32_16x16x32_f16(a0, WFRAG(0, 1, kb), accg0, 0, 0, 0);
            }
        } else {  // b == SEQ : layer1 only
            if (isD0) {
#pragma unroll 8
                for (int kb = 0; kb < 32; ++kb) {
                    half8 a1 = ld8(a1p + kb * 32);
                    half8 a2 = ld8(a2p + kb * 32);
                    acch1 = __builtin_amdgcn_mfma_f32_16x16x32_f16(a1, WFRAG(1, 0, kb), acch1, 0, 0, 0);
                    accg1 = __builtin_amdgcn_mfma_f32_16x16x32_f16(a1, WFRAG(1, 1, kb), accg1, 0, 0, 0);
                    acch1 = __builtin_amdgcn_mfma_f32_16x16x32_f16(a2, ld8(winp + (size_t)kb * 32), acch1, 0, 0, 0);
                    accg1 = __builtin_amdgcn_mfma_f32_16x16x32_f16(a2, ld8(winp + WGOFF + kb * 32), accg1, 0, 0, 0);
                }
            } else {
#pragma unroll 8
                for (int kb = 0; kb < 32; ++kb) {
                    half8 a1 = ld8(a1p + kb * 32);
                    acch1 = __builtin_amdgcn_mfma_f32_16x16x32_f16(a1, WFRAG(1, 0, kb), acch1, 0, 0, 0);
                    accg1 = __builtin_amdgcn_mfma_f32_16x16x32_f16(a1, WFRAG(1, 1, kb), accg1, 0, 0, 0);
                }
            }
        }

        float sn0v[4], sn1v[4];
        // ---- epilogue layer 0 (t = b): carry/mirror/sseq (consumed data) ----
        if (doL0) {
            _Float16* __restrict__ mw = ((gp0 + 1) & 1) ? m0b : m0a;
#pragma unroll
            for (int i = 0; i < 4; ++i) {
                const int gr = m0 + (lane >> 4) * 4 + i;
                const size_t idx = (size_t)gr * HID + colh;
                float ah = acch0[i] + bh0;
                float ag = accg0[i] + bg0;
                if (isD0) { ah += pre_h[i]; ag += pre_g[i]; }
                const float hv = 1.0f - __fdividef(2.0f, __expf(2.0f * ah) + 1.0f);
                const float gv = __fdividef(1.0f, 1.0f + __expf(-ag));
                const float sn = hv * gv + sold0[i] * (1.f - gv);
                sn0v[i] = sn;
                __hip_atomic_store(car0 + idx, sn, __ATOMIC_RELAXED,
                                   __HIP_MEMORY_SCOPE_AGENT);
                const unsigned short mine = __builtin_bit_cast(unsigned short, (_Float16)sn);
                const unsigned short oth = (unsigned short)__shfl_xor((int)mine, 1, 64);
                const uint32_t pk = (uint32_t)mine | ((uint32_t)oth << 16);
                if ((lane & 1) == 0) {
                    __hip_atomic_store(reinterpret_cast<uint32_t*>(mw + idx), pk,
                                       __ATOMIC_RELAXED, __HIP_MEMORY_SCOPE_AGENT);
                    if (d == 3) {
                        __hip_atomic_store(
                            reinterpret_cast<uint32_t*>(sseq + (size_t)b * SBUF + idx),
                            pk, __ATOMIC_RELAXED, __HIP_MEMORY_SCOPE_AGENT);
                    }
                }
            }
        }
        // ---- epilogue layer 1 (t = b-1): carry/mirror (consumed data) ----
        if (doL1) {
            _Float16* __restrict__ mw = ((gp1 + 1) & 1) ? m1b : m1a;
#pragma unroll
            for (int i = 0; i < 4; ++i) {
                const int gr = m0 + (lane >> 4) * 4 + i;
                const size_t idx = (size_t)gr * HID + colh;
                const float ah = acch1[i] + bh1;
                const float ag = accg1[i] + bg1;
                const float hv = 1.0f - __fdividef(2.0f, __expf(2.0f * ah) + 1.0f);
                const float gv = __fdividef(1.0f, 1.0f + __expf(-ag));
                const float sn = hv * gv + sold1[i] * (1.f - gv);
                sn1v[i] = sn;
                __hip_atomic_store(car1 + idx, sn, __ATOMIC_RELAXED,
                                   __HIP_MEMORY_SCOPE_AGENT);
                const unsigned short mine = __builtin_bit_cast(unsigned short, (_Float16)sn);
                const unsigned short oth = (unsigned short)__shfl_xor((int)mine, 1, 64);
                const uint32_t pk = (uint32_t)mine | ((uint32_t)oth << 16);
                if ((lane & 1) == 0) {
                    __hip_atomic_store(reinterpret_cast<uint32_t*>(mw + idx), pk,
                                       __ATOMIC_RELAXED, __HIP_MEMORY_SCOPE_AGENT);
                }
            }
        }
        __syncthreads();  // drain consumed-data stores (vmcnt 0) before arrive
        if (tid == 0)
            __hip_atomic_store(myf, b + 1, __ATOMIC_RELAXED, __HIP_MEMORY_SCOPE_AGENT);

        // ---- post-flag dead-end outputs (nobody reads these in-kernel):
        // their store-ack overlaps the next poll instead of the chain.
        if (d == 3) {
            if (doL1) {
#pragma unroll
                for (int i = 0; i < 4; ++i) {
                    const int gr = m0 + (lane >> 4) * 4 + i;
                    const size_t idx = (size_t)gr * HID + colh;
                    outp[(size_t)t1 * SBUF + idx] = sn1v[i];
                    if (t1 == SEQ - 1) fout1[idx] = sn1v[i];
                }
            }
            if (doL0 && b == SEQ - 1) {
#pragma unroll
                for (int i = 0; i < 4; ++i) {
                    const int gr = m0 + (lane >> 4) * 4 + i;
                    const size_t idx = (size_t)gr * HID + colh;
                    fout0[idx] = sn0v[i];
                }
            }
        }
    }
}

extern "C" void kernel_launch(void* const* d_in, const int* in_sizes, int n_in,
                              void* d_out, int out_size, void* d_ws, size_t ws_size,
                              hipStream_t stream) {
    (void)in_sizes; (void)n_in; (void)out_size; (void)ws_size;
    const float* x     = (const float*)d_in[0];
    const float* state = (const float*)d_in[1];
    const float* w_in  = (const float*)d_in[2];
    const float* w_h   = (const float*)d_in[3];
    const float* b_h   = (const float*)d_in[4];
    float* out = (float*)d_out;
    char* ws = (char*)d_ws;
    _Float16* Wt   = (_Float16*)ws;
    _Float16* HG0  = (_Float16*)(ws + OFF_HG0);
    _Float16* Sseq = (_Float16*)(ws + OFF_SSEQ);
    _Float16* mir0a = (_Float16*)(ws + OFF_MIR);
    _Float16* mir0b = mir0a + SBUF;
    _Float16* mir1a = mir0b + SBUF;
    _Float16* mir1b = mir1a + SBUF;
    float* car0 = (float*)(ws + OFF_CAR);
    float* car1 = car0 + SBUF;
    int* flags = (int*)(ws + OFF_CNT);

    (void)hipFuncSetAttribute((const void*)rhn_fused,
                              hipFuncAttributeMaxDynamicSharedMemorySize, 131072);

    wprep<<<10 * 64 * 32, 256, 0, stream>>>(w_in, w_h, Wt);
    sinit2<<<(SBUF + 255) / 256, 256, 0, stream>>>(state, mir0a, car0, mir1a, car1, flags);
    // HG0 = x @ w_in[0]
    gemm_proj<false><<<512 * 32, 256, 0, stream>>>((const void*)x, Wt + 0 * WSLOT, HG0);
    // fused two-layer pipelined scan
    rhn_fused<<<256, 256, 131072, stream>>>(
        Wt, b_h, HG0, Sseq, mir0a, mir0b, mir1a, mir1b, car0, car1, flags,
        out, out + (size_t)SEQ * SBUF, out + (size_t)SEQ * SBUF + SBUF);
}